// Round 5
// baseline (136.338 us; speedup 1.0000x reference)
//
#include <hip/hip_runtime.h>

using f32x4  = __attribute__((ext_vector_type(4))) float;
using h16x2  = __attribute__((ext_vector_type(2))) _Float16;
using h16x4  = __attribute__((ext_vector_type(4))) _Float16;
using h16x8  = __attribute__((ext_vector_type(8))) _Float16;
using fp16x2 = __attribute__((ext_vector_type(2))) __fp16;   // cvt_pkrtz result type

#define NEGBIG (-1e30f)
#define LOG2E  1.44269504f

constexpr int BH = 32, Nn = 2048, En = 64;

__device__ inline h16x8 cvt8(f32x4 x, f32x4 y) {
    union { h16x8 v; fp16x2 p[4]; } u;
    u.p[0] = __builtin_amdgcn_cvt_pkrtz(x[0], x[1]);
    u.p[1] = __builtin_amdgcn_cvt_pkrtz(x[2], x[3]);
    u.p[2] = __builtin_amdgcn_cvt_pkrtz(y[0], y[1]);
    u.p[3] = __builtin_amdgcn_cvt_pkrtz(y[2], y[3]);
    return u.v;
}
__device__ inline h16x4 cvt4(f32x4 x) {
    union { h16x4 v; fp16x2 p[2]; } u;
    u.p[0] = __builtin_amdgcn_cvt_pkrtz(x[0], x[1]);
    u.p[1] = __builtin_amdgcn_cvt_pkrtz(x[2], x[3]);
    return u.v;
}

// ---------------- split-K partial kernel ----------------
// Block: 512 thr = 8 waves; two 64-row q-subtiles share one K/V LDS stage.
// Grid: (N/128, BH, S). Each block: key chunk [s*chunk, min(seqlen,(s+1)*chunk)).
// Writes Opart (f16, O/L) + Wpart (f32, m + log2 L) to workspace.
__launch_bounds__(512)
__global__ void attn_part(const float* __restrict__ Qg,
                          const float* __restrict__ Kg,
                          const float* __restrict__ Vg,
                          const int*   __restrict__ seqlens,
                          _Float16*    __restrict__ Opart,
                          float*       __restrict__ Wpart,
                          int chunk)
{
    const int qblk = blockIdx.x;
    const int bh   = blockIdx.y;
    const int s    = blockIdx.z;
    const int seqlen = seqlens[bh >> 3];
    const int qstart = qblk * 128;
    const int kbeg   = s * chunk;
    if (qstart >= seqlen || kbeg >= seqlen) return;   // reduce fills zeros
    const int kend = min(seqlen, kbeg + chunk);

    const float* Qb = Qg + (size_t)bh * Nn * En;
    const float* Kb = Kg + (size_t)bh * Nn * En;
    const float* Vb = Vg + (size_t)bh * Nn * En;
    const int tid = threadIdx.x;

    __shared__ __attribute__((aligned(16))) _Float16 Ksh[64 * 64];
    __shared__ __attribute__((aligned(16))) _Float16 Vsh[64 * 64];

    const int wid  = tid >> 6;
    const int qsub = wid >> 2;
    const int widq = wid & 3;
    const int lane = tid & 63;
    const int lg   = lane >> 4;
    const int l16  = lane & 15;
    const bool active = (qstart + qsub * 64) < seqlen;

    const int qrow = qstart + qsub * 64 + widq * 16 + l16;
    h16x8 Qf[2];
    #pragma unroll
    for (int es = 0; es < 2; ++es) {
        const f32x4* qp = (const f32x4*)(Qb + (size_t)qrow * En + es * 32 + lg * 8);
        f32x4 x = qp[0] * LOG2E, y = qp[1] * LOG2E;
        Qf[es] = cvt8(x, y);
    }

    const int rK   = tid >> 3;
    const int cK   = tid & 7;
    const int vkey = tid & 63;
    const int ve0  = (tid >> 6) * 8;

    float m = NEGBIG, L = 0.f;
    f32x4 Ot[4] = {{0,0,0,0},{0,0,0,0},{0,0,0,0},{0,0,0,0}};

    auto loadStage = [&](int ks, f32x4& k0, f32x4& k1, f32x4& v0, f32x4& v1) {
        const f32x4* kp = (const f32x4*)(Kb + (size_t)(ks + rK) * En + cK * 8);
        k0 = kp[0]; k1 = kp[1];
        const f32x4* vp = (const f32x4*)(Vb + (size_t)(ks + vkey) * En + ve0);
        v0 = vp[0]; v1 = vp[1];
    };
    auto writeStage = [&](const f32x4& k0, const f32x4& k1,
                          const f32x4& v0, const f32x4& v1) {
        *(h16x8*)&Ksh[rK * 64 + ((cK ^ (rK & 7)) << 3)] = cvt8(k0, k1);
        float vv[8] = {v0[0], v0[1], v0[2], v0[3], v1[0], v1[1], v1[2], v1[3]};
        #pragma unroll
        for (int i = 0; i < 8; ++i) {
            int e = ve0 + i;
            Vsh[e * 64 + (((vkey >> 2) ^ (i << 1)) << 2) + (vkey & 3)] =
                (_Float16)vv[i];
        }
    };
    auto computeTile = [&](int ks) {
        if (!active) return;              // wave-uniform
        f32x4 St[4];
        #pragma unroll
        for (int kt = 0; kt < 4; ++kt) {
            f32x4 acc = {0, 0, 0, 0};
            int key = kt * 16 + l16;
            #pragma unroll
            for (int es = 0; es < 2; ++es) {
                int c = es * 4 + lg;
                h16x8 kf = *(const h16x8*)&Ksh[key * 64 + ((c ^ (key & 7)) << 3)];
                acc = __builtin_amdgcn_mfma_f32_16x16x32_f16(kf, Qf[es], acc, 0, 0, 0);
            }
            St[kt] = acc;
        }
        if (ks + 64 > seqlen) {
            #pragma unroll
            for (int kt = 0; kt < 4; ++kt) {
                int kb0 = ks + kt * 16 + lg * 4;
                #pragma unroll
                for (int j = 0; j < 4; ++j)
                    if (kb0 + j >= seqlen) St[kt][j] = NEGBIG;
            }
        }
        float tm = NEGBIG;
        #pragma unroll
        for (int kt = 0; kt < 4; ++kt)
            #pragma unroll
            for (int j = 0; j < 4; ++j) tm = fmaxf(tm, St[kt][j]);
        tm = fmaxf(tm, __shfl_xor(tm, 16));
        tm = fmaxf(tm, __shfl_xor(tm, 32));

        if (__any(tm > m + 8.f)) {        // defer-rescale (log2 domain)
            float mn = fmaxf(m, tm);
            float sc = __builtin_amdgcn_exp2f(m - mn);
            m = mn; L *= sc;
            #pragma unroll
            for (int et = 0; et < 4; ++et) Ot[et] *= sc;
        }
        float ps = 0.f;
        h16x4 Pf[4];
        #pragma unroll
        for (int kt = 0; kt < 4; ++kt) {
            float p0 = __builtin_amdgcn_exp2f(St[kt][0] - m);
            float p1 = __builtin_amdgcn_exp2f(St[kt][1] - m);
            float p2 = __builtin_amdgcn_exp2f(St[kt][2] - m);
            float p3 = __builtin_amdgcn_exp2f(St[kt][3] - m);
            ps += (p0 + p1) + (p2 + p3);
            union { h16x4 v; fp16x2 p[2]; } u;
            u.p[0] = __builtin_amdgcn_cvt_pkrtz(p0, p1);
            u.p[1] = __builtin_amdgcn_cvt_pkrtz(p2, p3);
            Pf[kt] = u.v;
        }
        ps += __shfl_xor(ps, 16);
        ps += __shfl_xor(ps, 32);
        L += ps;
        #pragma unroll
        for (int kt = 0; kt < 4; ++kt) {
            #pragma unroll
            for (int et = 0; et < 4; ++et) {
                int e  = et * 16 + l16;
                int c8 = kt * 4 + lg;
                h16x4 vf = *(const h16x4*)&Vsh[e * 64 + ((c8 ^ ((e & 7) << 1)) << 2)];
                Ot[et] = __builtin_amdgcn_mfma_f32_16x16x16f16(vf, Pf[kt], Ot[et], 0, 0, 0);
            }
        }
    };

    f32x4 kA0, kA1, vA0, vA1, kB0, kB1, vB0, vB1;
    loadStage(kbeg, kA0, kA1, vA0, vA1);
    int ks = kbeg;
    while (true) {
        __syncthreads();
        writeStage(kA0, kA1, vA0, vA1);
        if (ks + 64 < kend) loadStage(ks + 64, kB0, kB1, vB0, vB1);
        __syncthreads();
        computeTile(ks);
        ks += 64;
        if (ks >= kend) break;

        __syncthreads();
        writeStage(kB0, kB1, vB0, vB1);
        if (ks + 64 < kend) loadStage(ks + 64, kA0, kA1, vA0, vA1);
        __syncthreads();
        computeTile(ks);
        ks += 64;
        if (ks >= kend) break;
    }

    // epilogue: store normalized partial (f16) + log-weight
    if (active && qrow < seqlen) {
        float lw = m + __log2f(L);
        const size_t rbase = ((size_t)s * BH + bh) * Nn + qrow;
        if (lg == 0) Wpart[rbase] = lw;
        float invL = 1.f / L;
        _Float16* op = Opart + rbase * En;
        #pragma unroll
        for (int et = 0; et < 4; ++et) {
            f32x4 o = Ot[et] * invL;
            *(h16x4*)&op[et * 16 + lg * 4] = cvt4(o);
        }
    }
}

// ---------------- split-K reduction ----------------
// 256 thr: 32 rows/block, 8 threads/row (8 e each). Grid: BH*N/32.
__launch_bounds__(256)
__global__ void reduce_k(const _Float16* __restrict__ Opart,
                         const float*    __restrict__ Wpart,
                         const int*      __restrict__ seqlens,
                         float*          __restrict__ Og,
                         int cshift)
{
    const int tid  = threadIdx.x;
    const int r    = tid >> 3;
    const int e8   = tid & 7;
    const int grow = blockIdx.x * 32 + r;
    const int bh   = grow >> 11;
    const int row  = grow & (Nn - 1);
    const int seqlen = seqlens[bh >> 3];

    f32x4 a0 = {0, 0, 0, 0}, a1 = {0, 0, 0, 0};
    if (row < seqlen) {
        const int chunk = 1 << cshift;
        const int nlive = (seqlen + chunk - 1) >> cshift;
        float W = NEGBIG;
        for (int s = 0; s < nlive; ++s)
            W = fmaxf(W, Wpart[((size_t)s * BH + bh) * Nn + row]);
        float denom = 0.f;
        for (int s = 0; s < nlive; ++s) {
            const size_t rbase = ((size_t)s * BH + bh) * Nn + row;
            float a = __builtin_amdgcn_exp2f(Wpart[rbase] - W);
            denom += a;
            h16x8 o = *(const h16x8*)&Opart[rbase * En + e8 * 8];
            a0[0] += a * (float)o[0]; a0[1] += a * (float)o[1];
            a0[2] += a * (float)o[2]; a0[3] += a * (float)o[3];
            a1[0] += a * (float)o[4]; a1[1] += a * (float)o[5];
            a1[2] += a * (float)o[6]; a1[3] += a * (float)o[7];
        }
        float sc = 1.f / denom;
        a0 *= sc; a1 *= sc;
    }
    float* op = Og + ((size_t)bh * Nn + row) * En + e8 * 8;
    *(f32x4*)op       = a0;
    *(f32x4*)(op + 4) = a1;
}

// ---------------- fallback: single-pass (R3, known-good) ----------------
__launch_bounds__(512)
__global__ void attn_kernel(const float* __restrict__ Qg,
                            const float* __restrict__ Kg,
                            const float* __restrict__ Vg,
                            const int*   __restrict__ seqlens,
                            float*       __restrict__ Og)
{
    const int qblk = blockIdx.x;
    const int bh   = blockIdx.y;
    const int seqlen = seqlens[bh >> 3];
    const int qstart = qblk * 128;
    const int tid = threadIdx.x;
    float* Ob = Og + ((size_t)bh * Nn + qstart) * En;
    if (qstart >= seqlen) {
        f32x4 z = {0.f, 0.f, 0.f, 0.f};
        f32x4* op = (f32x4*)Ob;
        #pragma unroll
        for (int i = 0; i < 4; ++i) op[tid + i * 512] = z;
        return;
    }
    const float* Qb = Qg + (size_t)bh * Nn * En;
    const float* Kb = Kg + (size_t)bh * Nn * En;
    const float* Vb = Vg + (size_t)bh * Nn * En;
    __shared__ __attribute__((aligned(16))) _Float16 Ksh[64 * 64];
    __shared__ __attribute__((aligned(16))) _Float16 Vsh[64 * 64];
    const int wid  = tid >> 6;
    const int qsub = wid >> 2;
    const int widq = wid & 3;
    const int lane = tid & 63;
    const int lg   = lane >> 4;
    const int l16  = lane & 15;
    const bool active = (qstart + qsub * 64) < seqlen;
    const int qrow = qstart + qsub * 64 + widq * 16 + l16;
    h16x8 Qf[2];
    #pragma unroll
    for (int es = 0; es < 2; ++es) {
        const f32x4* qp = (const f32x4*)(Qb + (size_t)qrow * En + es * 32 + lg * 8);
        f32x4 x = qp[0] * LOG2E, y = qp[1] * LOG2E;
        Qf[es] = cvt8(x, y);
    }
    const int rK = tid >> 3, cK = tid & 7, vkey = tid & 63, ve0 = (tid >> 6) * 8;
    float m = NEGBIG, L = 0.f;
    f32x4 Ot[4] = {{0,0,0,0},{0,0,0,0},{0,0,0,0},{0,0,0,0}};
    auto loadStage = [&](int ks, f32x4& k0, f32x4& k1, f32x4& v0, f32x4& v1) {
        const f32x4* kp = (const f32x4*)(Kb + (size_t)(ks + rK) * En + cK * 8);
        k0 = kp[0]; k1 = kp[1];
        const f32x4* vp = (const f32x4*)(Vb + (size_t)(ks + vkey) * En + ve0);
        v0 = vp[0]; v1 = vp[1];
    };
    auto writeStage = [&](const f32x4& k0, const f32x4& k1,
                          const f32x4& v0, const f32x4& v1) {
        *(h16x8*)&Ksh[rK * 64 + ((cK ^ (rK & 7)) << 3)] = cvt8(k0, k1);
        float vv[8] = {v0[0], v0[1], v0[2], v0[3], v1[0], v1[1], v1[2], v1[3]};
        #pragma unroll
        for (int i = 0; i < 8; ++i) {
            int e = ve0 + i;
            Vsh[e * 64 + (((vkey >> 2) ^ (i << 1)) << 2) + (vkey & 3)] =
                (_Float16)vv[i];
        }
    };
    auto computeTile = [&](int ks) {
        if (!active) return;
        f32x4 St[4];
        #pragma unroll
        for (int kt = 0; kt < 4; ++kt) {
            f32x4 acc = {0, 0, 0, 0};
            int key = kt * 16 + l16;
            #pragma unroll
            for (int es = 0; es < 2; ++es) {
                int c = es * 4 + lg;
                h16x8 kf = *(const h16x8*)&Ksh[key * 64 + ((c ^ (key & 7)) << 3)];
                acc = __builtin_amdgcn_mfma_f32_16x16x32_f16(kf, Qf[es], acc, 0, 0, 0);
            }
            St[kt] = acc;
        }
        if (ks + 64 > seqlen) {
            #pragma unroll
            for (int kt = 0; kt < 4; ++kt) {
                int kb0 = ks + kt * 16 + lg * 4;
                #pragma unroll
                for (int j = 0; j < 4; ++j)
                    if (kb0 + j >= seqlen) St[kt][j] = NEGBIG;
            }
        }
        float tm = NEGBIG;
        #pragma unroll
        for (int kt = 0; kt < 4; ++kt)
            #pragma unroll
            for (int j = 0; j < 4; ++j) tm = fmaxf(tm, St[kt][j]);
        tm = fmaxf(tm, __shfl_xor(tm, 16));
        tm = fmaxf(tm, __shfl_xor(tm, 32));
        if (__any(tm > m + 8.f)) {
            float mn = fmaxf(m, tm);
            float sc = __builtin_amdgcn_exp2f(m - mn);
            m = mn; L *= sc;
            #pragma unroll
            for (int et = 0; et < 4; ++et) Ot[et] *= sc;
        }
        float ps = 0.f;
        h16x4 Pf[4];
        #pragma unroll
        for (int kt = 0; kt < 4; ++kt) {
            float p0 = __builtin_amdgcn_exp2f(St[kt][0] - m);
            float p1 = __builtin_amdgcn_exp2f(St[kt][1] - m);
            float p2 = __builtin_amdgcn_exp2f(St[kt][2] - m);
            float p3 = __builtin_amdgcn_exp2f(St[kt][3] - m);
            ps += (p0 + p1) + (p2 + p3);
            union { h16x4 v; fp16x2 p[2]; } u;
            u.p[0] = __builtin_amdgcn_cvt_pkrtz(p0, p1);
            u.p[1] = __builtin_amdgcn_cvt_pkrtz(p2, p3);
            Pf[kt] = u.v;
        }
        ps += __shfl_xor(ps, 16);
        ps += __shfl_xor(ps, 32);
        L += ps;
        #pragma unroll
        for (int kt = 0; kt < 4; ++kt) {
            #pragma unroll
            for (int et = 0; et < 4; ++et) {
                int e  = et * 16 + l16;
                int c8 = kt * 4 + lg;
                h16x4 vf = *(const h16x4*)&Vsh[e * 64 + ((c8 ^ ((e & 7) << 1)) << 2)];
                Ot[et] = __builtin_amdgcn_mfma_f32_16x16x16f16(vf, Pf[kt], Ot[et], 0, 0, 0);
            }
        }
    };
    f32x4 kA0, kA1, vA0, vA1, kB0, kB1, vB0, vB1;
    loadStage(0, kA0, kA1, vA0, vA1);
    int ks = 0;
    while (true) {
        __syncthreads();
        writeStage(kA0, kA1, vA0, vA1);
        if (ks + 64 < seqlen) loadStage(ks + 64, kB0, kB1, vB0, vB1);
        __syncthreads();
        computeTile(ks);
        ks += 64;
        if (ks >= seqlen) break;
        __syncthreads();
        writeStage(kB0, kB1, vB0, vB1);
        if (ks + 64 < seqlen) loadStage(ks + 64, kA0, kA1, vA0, vA1);
        __syncthreads();
        computeTile(ks);
        ks += 64;
        if (ks >= seqlen) break;
    }
    float invL = 1.f / L;
    float* orow = Ob + (size_t)(qsub * 64 + widq * 16 + l16) * En;
    if (qrow < seqlen) {
        #pragma unroll
        for (int et = 0; et < 4; ++et) {
            f32x4 o = Ot[et] * invL;
            *(f32x4*)(orow + et * 16 + lg * 4) = o;
        }
    } else {
        f32x4 z = {0, 0, 0, 0};
        #pragma unroll
        for (int et = 0; et < 4; ++et)
            *(f32x4*)(orow + et * 16 + lg * 4) = z;
    }
}

extern "C" void kernel_launch(void* const* d_in, const int* in_sizes, int n_in,
                              void* d_out, int out_size, void* d_ws, size_t ws_size,
                              hipStream_t stream)
{
    const float* Q  = (const float*)d_in[0];
    const float* K  = (const float*)d_in[1];
    const float* V  = (const float*)d_in[2];
    const int*   SL = (const int*)d_in[3];
    float*       O  = (float*)d_out;

    auto need = [](int S) {
        return (size_t)S * BH * Nn * En * sizeof(_Float16)
             + (size_t)S * BH * Nn * sizeof(float);
    };
    int S = 0;
    if      (ws_size >= need(4)) S = 4;
    else if (ws_size >= need(2)) S = 2;

    if (S) {
        _Float16* Opart = (_Float16*)d_ws;
        float*    Wpart = (float*)((char*)d_ws
                            + (size_t)S * BH * Nn * En * sizeof(_Float16));
        const int chunk  = Nn / S;
        const int cshift = (S == 4) ? 9 : 10;
        attn_part<<<dim3(Nn / 128, BH, S), 512, 0, stream>>>(
            Q, K, V, SL, Opart, Wpart, chunk);
        reduce_k<<<dim3(BH * Nn / 32), 256, 0, stream>>>(
            Opart, Wpart, SL, O, cshift);
    } else {
        attn_kernel<<<dim3(Nn / 128, BH), 512, 0, stream>>>(Q, K, V, SL, O);
    }
}

// Round 6
// 132.564 us; speedup vs baseline: 1.0285x; 1.0285x over previous
//
#include <hip/hip_runtime.h>

using f32x4  = __attribute__((ext_vector_type(4))) float;
using f32x16 = __attribute__((ext_vector_type(16))) float;
using h16x2  = __attribute__((ext_vector_type(2))) _Float16;
using h16x4  = __attribute__((ext_vector_type(4))) _Float16;
using h16x8  = __attribute__((ext_vector_type(8))) _Float16;
using fp16x2 = __attribute__((ext_vector_type(2))) __fp16;   // cvt_pkrtz result type

#define NEGBIG (-1e30f)
#define LOG2E  1.44269504f

constexpr int BH = 32, Nn = 2048, En = 64;

__device__ inline h16x8 cvt8(f32x4 x, f32x4 y) {
    union { h16x8 v; fp16x2 p[4]; } u;
    u.p[0] = __builtin_amdgcn_cvt_pkrtz(x[0], x[1]);
    u.p[1] = __builtin_amdgcn_cvt_pkrtz(x[2], x[3]);
    u.p[2] = __builtin_amdgcn_cvt_pkrtz(y[0], y[1]);
    u.p[3] = __builtin_amdgcn_cvt_pkrtz(y[2], y[3]);
    return u.v;
}
__device__ inline h16x4 cvt4(f32x4 x) {
    union { h16x4 v; fp16x2 p[2]; } u;
    u.p[0] = __builtin_amdgcn_cvt_pkrtz(x[0], x[1]);
    u.p[1] = __builtin_amdgcn_cvt_pkrtz(x[2], x[3]);
    return u.v;
}
__device__ inline fp16x2 shfl32(fp16x2 x) {
    union { fp16x2 h; int i; } u; u.h = x;
    u.i = __shfl_xor(u.i, 32);
    return u.h;
}

// lgkm-only barrier: ds_writes visible, but register-destined global loads
// stay IN FLIGHT across the barrier (no vmcnt(0) drain).
#define TILE_BARRIER() asm volatile("s_waitcnt lgkmcnt(0)\ns_barrier" ::: "memory")

// ---------------- split-K partial kernel (32x32 MFMA, 4 waves) ----------------
// Block: 256 thr = 4 waves; each wave owns 32 q-rows (128 q/block).
// Grid: (N/128, BH, S). Key chunk [s*chunk, min(seqlen,(s+1)*chunk)).
__launch_bounds__(256, 3)
__global__ void attn_part(const float* __restrict__ Qg,
                          const float* __restrict__ Kg,
                          const float* __restrict__ Vg,
                          const int*   __restrict__ seqlens,
                          _Float16*    __restrict__ Opart,
                          float*       __restrict__ Wpart,
                          int chunk)
{
    const int qblk = blockIdx.x;
    const int bh   = blockIdx.y;
    const int s    = blockIdx.z;
    const int seqlen = seqlens[bh >> 3];
    const int qstart = qblk * 128;
    const int kbeg   = s * chunk;
    if (qstart >= seqlen || kbeg >= seqlen) return;   // reduce fills zeros
    const int kend = min(seqlen, kbeg + chunk);

    const float* Qb = Qg + (size_t)bh * Nn * En;
    const float* Kb = Kg + (size_t)bh * Nn * En;
    const float* Vb = Vg + (size_t)bh * Nn * En;
    const int tid = threadIdx.x;

    // K: [key][e] f16, 8-half chunks swizzled c^(key&7).
    // V: [e][key] f16, 4-half (4-key) chunks swizzled c4^((e&7)<<1).
    __shared__ __attribute__((aligned(16))) _Float16 Ksh[2][64 * 64];
    __shared__ __attribute__((aligned(16))) _Float16 Vsh[2][64 * 64];

    const int wid  = tid >> 6;
    const int lane = tid & 63;
    const int l31  = lane & 31;
    const int h    = lane >> 5;

    const int qbase = qstart + wid * 32;
    const bool active = qbase < seqlen;               // wave-uniform
    const int qrow = qbase + l31;                     // q owned by this lane

    // Q fragments (B operand 32x32x16), pre-scaled by log2(e):
    // B[k=16*es+8*h+j][col=q=l31]
    h16x8 Qf[4];
    #pragma unroll
    for (int es = 0; es < 4; ++es) {
        const f32x4* qp = (const f32x4*)(Qb + (size_t)qrow * En + es * 16 + h * 8);
        f32x4 x = qp[0] * LOG2E, y = qp[1] * LOG2E;
        Qf[es] = cvt8(x, y);
    }

    // staging assignment (256 threads, 2 iterations each):
    const int vkey = tid & 63;
    const int vw   = tid >> 6;        // e-octet base = vw*8 + 32*it

    const f32x16 z16 = {0,0,0,0,0,0,0,0,0,0,0,0,0,0,0,0};
    float m = NEGBIG, L = 0.f;
    f32x16 Ot[2] = {z16, z16};

    f32x4 kr[2][2], vr[2][2];         // prefetch registers (one tile)

    auto loadStage = [&](int ks) {
        #pragma unroll
        for (int it = 0; it < 2; ++it) {
            int cid = tid + 256 * it;
            int r = cid >> 3, c = cid & 7;
            const f32x4* kp = (const f32x4*)(Kb + (size_t)(ks + r) * En + c * 8);
            kr[it][0] = kp[0]; kr[it][1] = kp[1];
            const f32x4* vp = (const f32x4*)(Vb + (size_t)(ks + vkey) * En + vw * 8 + 32 * it);
            vr[it][0] = vp[0]; vr[it][1] = vp[1];
        }
    };

    auto writeStage = [&](int db) {
        #pragma unroll
        for (int it = 0; it < 2; ++it) {
            int cid = tid + 256 * it;
            int r = cid >> 3, c = cid & 7;
            *(h16x8*)&Ksh[db][r * 64 + ((c ^ (r & 7)) << 3)] = cvt8(kr[it][0], kr[it][1]);
            int e0 = vw * 8 + 32 * it;
            float vv[8] = {vr[it][0][0], vr[it][0][1], vr[it][0][2], vr[it][0][3],
                           vr[it][1][0], vr[it][1][1], vr[it][1][2], vr[it][1][3]};
            #pragma unroll
            for (int i = 0; i < 8; ++i) {   // e&7 == i (e0 multiple of 8/32)
                int e = e0 + i;
                Vsh[db][e * 64 + (((vkey >> 2) ^ (i << 1)) << 2) + (vkey & 3)] =
                    (_Float16)vv[i];
            }
        }
    };

    auto computeTile = [&](int db, int ks) {
        if (!active) return;              // wave-uniform; no barriers inside
        const _Float16* Kl = Ksh[db];
        const _Float16* Vl = Vsh[db];

        // ---- S'^T = K · (Q·log2e)^T : 32x32x16, kt = 32-key block ----
        f32x16 St[2];
        #pragma unroll
        for (int kt = 0; kt < 2; ++kt) {
            f32x16 acc = z16;
            #pragma unroll
            for (int es = 0; es < 4; ++es) {
                // A[row=key=32kt+l31][k=e=16es+8h+j]
                h16x8 kf = *(const h16x8*)
                    &Kl[(32 * kt + l31) * 64 + ((((es << 1) + h) ^ (l31 & 7)) << 3)];
                acc = __builtin_amdgcn_mfma_f32_32x32x16_f16(kf, Qf[es], acc, 0, 0, 0);
            }
            St[kt] = acc;
        }
        // D layout: col=q=l31, row(key within 32-blk) = (r&3)+8*(r>>2)+4*h
        if (ks + 64 > seqlen) {           // tail-tile key mask
            #pragma unroll
            for (int kt = 0; kt < 2; ++kt) {
                #pragma unroll
                for (int r = 0; r < 16; ++r) {
                    int key = ks + 32 * kt + 4 * h + ((r & 3) + 8 * (r >> 2));
                    if (key >= seqlen) St[kt][r] = NEGBIG;
                }
            }
        }

        // ---- online softmax (log2 domain; lane pair l<->l^32 shares q) ----
        float tm = St[0][0];
        #pragma unroll
        for (int r = 1; r < 16; ++r) tm = fmaxf(tm, St[0][r]);
        #pragma unroll
        for (int r = 0; r < 16; ++r) tm = fmaxf(tm, St[1][r]);
        tm = fmaxf(tm, __shfl_xor(tm, 32));

        if (__any(tm > m + 8.f)) {        // defer-rescale (THR=8)
            float mn = fmaxf(m, tm);
            float sc = __builtin_amdgcn_exp2f(m - mn);
            m = mn; L *= sc;
            Ot[0] *= sc; Ot[1] *= sc;
        }

        float ps = 0.f;
        fp16x2 pk[2][8];
        #pragma unroll
        for (int kt = 0; kt < 2; ++kt) {
            #pragma unroll
            for (int mm = 0; mm < 8; ++mm) {
                float p0 = __builtin_amdgcn_exp2f(St[kt][2 * mm]     - m);
                float p1 = __builtin_amdgcn_exp2f(St[kt][2 * mm + 1] - m);
                ps += p0 + p1;
                pk[kt][mm] = __builtin_amdgcn_cvt_pkrtz(p0, p1);
            }
        }
        ps += __shfl_xor(ps, 32);
        L += ps;

        // ---- O^T += V^T · P^T (32x32x16); B needs keys 16*kstep+8*h+j ----
        #pragma unroll
        for (int kstep = 0; kstep < 4; ++kstep) {
            const int kt = kstep >> 1, k4 = (kstep & 1) * 4;
            fp16x2 sendA = h ? pk[kt][k4 + 0] : pk[kt][k4 + 2];
            fp16x2 sendB = h ? pk[kt][k4 + 1] : pk[kt][k4 + 3];
            fp16x2 recvA = shfl32(sendA);
            fp16x2 recvB = shfl32(sendB);
            fp16x2 ownLo = h ? pk[kt][k4 + 2] : pk[kt][k4 + 0];
            fp16x2 ownHi = h ? pk[kt][k4 + 3] : pk[kt][k4 + 1];
            union { h16x8 v; fp16x2 d[4]; } pf;
            pf.d[0] = h ? recvA : ownLo;
            pf.d[1] = h ? recvB : ownHi;
            pf.d[2] = h ? ownLo : recvA;
            pf.d[3] = h ? ownHi : recvB;
            #pragma unroll
            for (int et = 0; et < 2; ++et) {
                // A[row=e=32et+l31][k=key=16kstep+8h+j]
                h16x8 vf = *(const h16x8*)
                    &Vl[(32 * et + l31) * 64 +
                        ((((kstep << 2) + (h << 1)) ^ ((l31 & 7) << 1)) << 2)];
                Ot[et] = __builtin_amdgcn_mfma_f32_32x32x16_f16(vf, pf.v, Ot[et], 0, 0, 0);
            }
        }
    };

    // ---- pipelined K loop: 1 barrier/tile; loads in flight across it ----
    int ks = kbeg, db = 0;
    loadStage(ks);
    while (true) {
        writeStage(db);
        if (ks + 64 < kend) loadStage(ks + 64);
        TILE_BARRIER();
        computeTile(db, ks);
        ks += 64;
        if (ks >= kend) break;
        db ^= 1;
    }

    // ---- epilogue: Ot[et][r] = O^T[e = 32et+8(r>>2)+4h+(r&3)][q=l31] ----
    if (active && qrow < seqlen) {
        float lw = m + __log2f(L);
        const size_t rbase = ((size_t)s * BH + bh) * Nn + qrow;
        if (h == 0) Wpart[rbase] = lw;
        float invL = 1.f / L;
        _Float16* op = Opart + rbase * En;
        #pragma unroll
        for (int et = 0; et < 2; ++et) {
            #pragma unroll
            for (int r1 = 0; r1 < 4; ++r1) {
                f32x4 o = {Ot[et][4 * r1 + 0] * invL, Ot[et][4 * r1 + 1] * invL,
                           Ot[et][4 * r1 + 2] * invL, Ot[et][4 * r1 + 3] * invL};
                *(h16x4*)&op[et * 32 + r1 * 8 + h * 4] = cvt4(o);
            }
        }
    }
}

// ---------------- split-K reduction (unchanged, proven) ----------------
__launch_bounds__(256)
__global__ void reduce_k(const _Float16* __restrict__ Opart,
                         const float*    __restrict__ Wpart,
                         const int*      __restrict__ seqlens,
                         float*          __restrict__ Og,
                         int cshift)
{
    const int tid  = threadIdx.x;
    const int r    = tid >> 3;
    const int e8   = tid & 7;
    const int grow = blockIdx.x * 32 + r;
    const int bh   = grow >> 11;
    const int row  = grow & (Nn - 1);
    const int seqlen = seqlens[bh >> 3];

    f32x4 a0 = {0, 0, 0, 0}, a1 = {0, 0, 0, 0};
    if (row < seqlen) {
        const int chunk = 1 << cshift;
        const int nlive = (seqlen + chunk - 1) >> cshift;
        float W = NEGBIG;
        for (int s = 0; s < nlive; ++s)
            W = fmaxf(W, Wpart[((size_t)s * BH + bh) * Nn + row]);
        float denom = 0.f;
        for (int s = 0; s < nlive; ++s) {
            const size_t rbase = ((size_t)s * BH + bh) * Nn + row;
            float a = __builtin_amdgcn_exp2f(Wpart[rbase] - W);
            denom += a;
            h16x8 o = *(const h16x8*)&Opart[rbase * En + e8 * 8];
            a0[0] += a * (float)o[0]; a0[1] += a * (float)o[1];
            a0[2] += a * (float)o[2]; a0[3] += a * (float)o[3];
            a1[0] += a * (float)o[4]; a1[1] += a * (float)o[5];
            a1[2] += a * (float)o[6]; a1[3] += a * (float)o[7];
        }
        float sc = 1.f / denom;
        a0 *= sc; a1 *= sc;
    }
    float* op = Og + ((size_t)bh * Nn + row) * En + e8 * 8;
    *(f32x4*)op       = a0;
    *(f32x4*)(op + 4) = a1;
}

// ---------------- fallback: single-pass (R3/R5, known-good) ----------------
__launch_bounds__(512)
__global__ void attn_kernel(const float* __restrict__ Qg,
                            const float* __restrict__ Kg,
                            const float* __restrict__ Vg,
                            const int*   __restrict__ seqlens,
                            float*       __restrict__ Og)
{
    const int qblk = blockIdx.x;
    const int bh   = blockIdx.y;
    const int seqlen = seqlens[bh >> 3];
    const int qstart = qblk * 128;
    const int tid = threadIdx.x;
    float* Ob = Og + ((size_t)bh * Nn + qstart) * En;
    if (qstart >= seqlen) {
        f32x4 z = {0.f, 0.f, 0.f, 0.f};
        f32x4* op = (f32x4*)Ob;
        #pragma unroll
        for (int i = 0; i < 4; ++i) op[tid + i * 512] = z;
        return;
    }
    const float* Qb = Qg + (size_t)bh * Nn * En;
    const float* Kb = Kg + (size_t)bh * Nn * En;
    const float* Vb = Vg + (size_t)bh * Nn * En;
    __shared__ __attribute__((aligned(16))) _Float16 Ksh[64 * 64];
    __shared__ __attribute__((aligned(16))) _Float16 Vsh[64 * 64];
    const int wid  = tid >> 6;
    const int qsub = wid >> 2;
    const int widq = wid & 3;
    const int lane = tid & 63;
    const int lg   = lane >> 4;
    const int l16  = lane & 15;
    const bool active = (qstart + qsub * 64) < seqlen;
    const int qrow = qstart + qsub * 64 + widq * 16 + l16;
    h16x8 Qf[2];
    #pragma unroll
    for (int es = 0; es < 2; ++es) {
        const f32x4* qp = (const f32x4*)(Qb + (size_t)qrow * En + es * 32 + lg * 8);
        f32x4 x = qp[0] * LOG2E, y = qp[1] * LOG2E;
        Qf[es] = cvt8(x, y);
    }
    const int rK = tid >> 3, cK = tid & 7, vkey = tid & 63, ve0 = (tid >> 6) * 8;
    float m = NEGBIG, L = 0.f;
    f32x4 Ot[4] = {{0,0,0,0},{0,0,0,0},{0,0,0,0},{0,0,0,0}};
    auto loadStage = [&](int ks, f32x4& k0, f32x4& k1, f32x4& v0, f32x4& v1) {
        const f32x4* kp = (const f32x4*)(Kb + (size_t)(ks + rK) * En + cK * 8);
        k0 = kp[0]; k1 = kp[1];
        const f32x4* vp = (const f32x4*)(Vb + (size_t)(ks + vkey) * En + ve0);
        v0 = vp[0]; v1 = vp[1];
    };
    auto writeStage = [&](const f32x4& k0, const f32x4& k1,
                          const f32x4& v0, const f32x4& v1) {
        *(h16x8*)&Ksh[rK * 64 + ((cK ^ (rK & 7)) << 3)] = cvt8(k0, k1);
        float vv[8] = {v0[0], v0[1], v0[2], v0[3], v1[0], v1[1], v1[2], v1[3]};
        #pragma unroll
        for (int i = 0; i < 8; ++i) {
            int e = ve0 + i;
            Vsh[e * 64 + (((vkey >> 2) ^ (i << 1)) << 2) + (vkey & 3)] =
                (_Float16)vv[i];
        }
    };
    auto computeTile = [&](int ks) {
        if (!active) return;
        f32x4 St[4];
        #pragma unroll
        for (int kt = 0; kt < 4; ++kt) {
            f32x4 acc = {0, 0, 0, 0};
            int key = kt * 16 + l16;
            #pragma unroll
            for (int es = 0; es < 2; ++es) {
                int c = es * 4 + lg;
                h16x8 kf = *(const h16x8*)&Ksh[key * 64 + ((c ^ (key & 7)) << 3)];
                acc = __builtin_amdgcn_mfma_f32_16x16x32_f16(kf, Qf[es], acc, 0, 0, 0);
            }
            St[kt] = acc;
        }
        if (ks + 64 > seqlen) {
            #pragma unroll
            for (int kt = 0; kt < 4; ++kt) {
                int kb0 = ks + kt * 16 + lg * 4;
                #pragma unroll
                for (int j = 0; j < 4; ++j)
                    if (kb0 + j >= seqlen) St[kt][j] = NEGBIG;
            }
        }
        float tm = NEGBIG;
        #pragma unroll
        for (int kt = 0; kt < 4; ++kt)
            #pragma unroll
            for (int j = 0; j < 4; ++j) tm = fmaxf(tm, St[kt][j]);
        tm = fmaxf(tm, __shfl_xor(tm, 16));
        tm = fmaxf(tm, __shfl_xor(tm, 32));
        if (__any(tm > m + 8.f)) {
            float mn = fmaxf(m, tm);
            float sc = __builtin_amdgcn_exp2f(m - mn);
            m = mn; L *= sc;
            #pragma unroll
            for (int et = 0; et < 4; ++et) Ot[et] *= sc;
        }
        float ps = 0.f;
        h16x4 Pf[4];
        #pragma unroll
        for (int kt = 0; kt < 4; ++kt) {
            float p0 = __builtin_amdgcn_exp2f(St[kt][0] - m);
            float p1 = __builtin_amdgcn_exp2f(St[kt][1] - m);
            float p2 = __builtin_amdgcn_exp2f(St[kt][2] - m);
            float p3 = __builtin_amdgcn_exp2f(St[kt][3] - m);
            ps += (p0 + p1) + (p2 + p3);
            union { h16x4 v; fp16x2 p[2]; } u;
            u.p[0] = __builtin_amdgcn_cvt_pkrtz(p0, p1);
            u.p[1] = __builtin_amdgcn_cvt_pkrtz(p2, p3);
            Pf[kt] = u.v;
        }
        ps += __shfl_xor(ps, 16);
        ps += __shfl_xor(ps, 32);
        L += ps;
        #pragma unroll
        for (int kt = 0; kt < 4; ++kt) {
            #pragma unroll
            for (int et = 0; et < 4; ++et) {
                int e  = et * 16 + l16;
                int c8 = kt * 4 + lg;
                h16x4 vf = *(const h16x4*)&Vsh[e * 64 + ((c8 ^ ((e & 7) << 1)) << 2)];
                Ot[et] = __builtin_amdgcn_mfma_f32_16x16x16f16(vf, Pf[kt], Ot[et], 0, 0, 0);
            }
        }
    };
    f32x4 kA0, kA1, vA0, vA1, kB0, kB1, vB0, vB1;
    loadStage(0, kA0, kA1, vA0, vA1);
    int ks = 0;
    while (true) {
        __syncthreads();
        writeStage(kA0, kA1, vA0, vA1);
        if (ks + 64 < seqlen) loadStage(ks + 64, kB0, kB1, vB0, vB1);
        __syncthreads();
        computeTile(ks);
        ks += 64;
        if (ks >= seqlen) break;
        __syncthreads();
        writeStage(kB0, kB1, vB0, vB1);
        if (ks + 64 < seqlen) loadStage(ks + 64, kA0, kA1, vA0, vA1);
        __syncthreads();
        computeTile(ks);
        ks += 64;
        if (ks >= seqlen) break;
    }
    float invL = 1.f / L;
    float* orow = Ob + (size_t)(qsub * 64 + widq * 16 + l16) * En;
    if (qrow < seqlen) {
        #pragma unroll
        for (int et = 0; et < 4; ++et) {
            f32x4 o = Ot[et] * invL;
            *(f32x4*)(orow + et * 16 + lg * 4) = o;
        }
    } else {
        f32x4 z = {0, 0, 0, 0};
        #pragma unroll
        for (int et = 0; et < 4; ++et)
            *(f32x4*)(orow + et * 16 + lg * 4) = z;
    }
}

extern "C" void kernel_launch(void* const* d_in, const int* in_sizes, int n_in,
                              void* d_out, int out_size, void* d_ws, size_t ws_size,
                              hipStream_t stream)
{
    const float* Q  = (const float*)d_in[0];
    const float* K  = (const float*)d_in[1];
    const float* V  = (const float*)d_in[2];
    const int*   SL = (const int*)d_in[3];
    float*       O  = (float*)d_out;

    auto need = [](int S) {
        return (size_t)S * BH * Nn * En * sizeof(_Float16)
             + (size_t)S * BH * Nn * sizeof(float);
    };
    int S = 0;
    if      (ws_size >= need(4)) S = 4;
    else if (ws_size >= need(2)) S = 2;

    if (S) {
        _Float16* Opart = (_Float16*)d_ws;
        float*    Wpart = (float*)((char*)d_ws
                            + (size_t)S * BH * Nn * En * sizeof(_Float16));
        const int chunk  = Nn / S;
        const int cshift = (S == 4) ? 9 : 10;
        attn_part<<<dim3(Nn / 128, BH, S), 256, 0, stream>>>(
            Q, K, V, SL, Opart, Wpart, chunk);
        reduce_k<<<dim3(BH * Nn / 32), 256, 0, stream>>>(
            Opart, Wpart, SL, O, cshift);
    } else {
        attn_kernel<<<dim3(Nn / 128, BH), 512, 0, stream>>>(Q, K, V, SL, O);
    }
}